// Round 1
// baseline (567.775 us; speedup 1.0000x reference)
//
#include <hip/hip_runtime.h>
#include <hip/hip_bf16.h>

// ---------------------------------------------------------------------------
// GCN: 3x gcn_conv + global_mean_pool + linear
//   h' = D^-1/2 (A+I) D^-1/2 (h W) + b
// Rewritten: layer1 aggregates BEFORE GEMM ((AX)W == A(XW)), layers 2/3 after.
// CSR-by-dst built per call (deterministic structure), gather-based aggregation.
// ---------------------------------------------------------------------------

#define N_NODES_C  20000
#define N_EDGES_C  320000
#define N_GRAPHS_C 64
#define F_IN_C     128
#define HID_C      512

__global__ void zero_int_kernel(int* __restrict__ p, int n) {
    int i = blockIdx.x * blockDim.x + threadIdx.x;
    if (i < n) p[i] = 0;
}

__global__ void count_kernel(const int* __restrict__ dst, int* __restrict__ deg_cnt, int E) {
    int e = blockIdx.x * blockDim.x + threadIdx.x;
    if (e < E) atomicAdd(&deg_cnt[dst[e]], 1);
}

// Single-block exclusive scan over deg_cnt -> row_ptr (+cursor copy), dinv = rsqrt(cnt+1)
__global__ __launch_bounds__(1024) void scan_kernel(const int* __restrict__ deg_cnt,
                                                    int* __restrict__ row_ptr,
                                                    int* __restrict__ cursor,
                                                    float* __restrict__ dinv, int n) {
    __shared__ int sd[1024];
    int t = threadIdx.x;
    int carry = 0;
    for (int base = 0; base < n; base += 1024) {
        int idx = base + t;
        int v = (idx < n) ? deg_cnt[idx] : 0;
        sd[t] = v;
        __syncthreads();
        #pragma unroll
        for (int off = 1; off < 1024; off <<= 1) {
            int x = sd[t];
            if (t >= off) x += sd[t - off];
            __syncthreads();
            sd[t] = x;
            __syncthreads();
        }
        int incl = sd[t];
        int excl = incl - v;
        if (idx < n) {
            int rp = carry + excl;
            row_ptr[idx] = rp;
            cursor[idx]  = rp;
            dinv[idx]    = rsqrtf((float)(v + 1));  // +1 self-loop; deg always > 0
        }
        carry += sd[1023];
        __syncthreads();
    }
    if (t == 0) row_ptr[n] = carry;
}

__global__ void fill_kernel(const int* __restrict__ src, const int* __restrict__ dst,
                            int* __restrict__ cursor, int* __restrict__ col_idx, int E) {
    int e = blockIdx.x * blockDim.x + threadIdx.x;
    if (e >= E) return;
    int d = dst[e];
    int pos = atomicAdd(&cursor[d], 1);
    col_idx[pos] = src[e];
}

// graph start offsets from sorted batch; gstart has ngraphs+1 entries
__global__ void bounds_kernel(const int* __restrict__ batch, int n, int ngraphs,
                              int* __restrict__ gstart) {
    int i = blockIdx.x * blockDim.x + threadIdx.x;
    if (i >= n) return;
    int b = batch[i];
    if (i == 0) {
        for (int g = 0; g <= b; ++g) gstart[g] = 0;
    } else {
        int bp = batch[i - 1];
        if (bp != b) for (int g = bp + 1; g <= b; ++g) gstart[g] = i;
    }
    if (i == n - 1) {
        for (int g = b + 1; g <= ngraphs; ++g) gstart[g] = n;
    }
}

// out[i] = dinv[i] * ( sum_{e in in(i)} h[src]*dinv[src] + dinv[i]*h[i] ) (+bias)(relu)
template <int F, bool BIAS, bool RELU>
__global__ void agg_kernel(const float* __restrict__ h, const float* __restrict__ dinv,
                           const int* __restrict__ row_ptr, const int* __restrict__ col_idx,
                           const float* __restrict__ bias, float* __restrict__ out, int n) {
    int i = blockIdx.x;
    int c = threadIdx.x;   // blockDim == F
    float di = dinv[i];
    float s = di * h[(size_t)i * F + c];   // self-loop term (pre-final-scale)
    int e0 = row_ptr[i], e1 = row_ptr[i + 1];
    for (int e = e0; e < e1; ++e) {
        int src = col_idx[e];
        s = fmaf(h[(size_t)src * F + c], dinv[src], s);
    }
    s *= di;
    if (BIAS) s += bias[c];
    if (RELU) s = fmaxf(s, 0.f);
    out[(size_t)i * F + c] = s;
}

// f32 SIMT GEMM: C[M,N] = A[M,K] @ W[K,N] (+bias)(relu). BM=BN=128, BK=8,
// 256 threads, 8x8 micro-tile per thread.
template <int K, int N, bool BIAS, bool RELU>
__global__ __launch_bounds__(256) void gemm_kernel(const float* __restrict__ A,
                                                   const float* __restrict__ W,
                                                   const float* __restrict__ bias,
                                                   float* __restrict__ C, int M) {
    constexpr int BM = 128, BN = 128, BK = 8;
    __shared__ float As[BK][BM + 4];
    __shared__ float Bs[BK][BN];
    int tid = threadIdx.x;
    int bm = blockIdx.x * BM;
    int bn = blockIdx.y * BN;
    int tx = tid & 15, ty = tid >> 4;

    float acc[8][8] = {};
    int m_a = tid >> 1;            // 0..127
    int k_a = (tid & 1) * 4;       // 0 or 4
    int k_b = tid >> 5;            // 0..7
    int n_b = (tid & 31) * 4;      // 0..124

    for (int k0 = 0; k0 < K; k0 += BK) {
        int gm = bm + m_a;
        float4 av = make_float4(0.f, 0.f, 0.f, 0.f);
        if (gm < M) av = *reinterpret_cast<const float4*>(&A[(size_t)gm * K + k0 + k_a]);
        As[k_a + 0][m_a] = av.x;
        As[k_a + 1][m_a] = av.y;
        As[k_a + 2][m_a] = av.z;
        As[k_a + 3][m_a] = av.w;
        float4 bv = *reinterpret_cast<const float4*>(&W[(size_t)(k0 + k_b) * N + bn + n_b]);
        *reinterpret_cast<float4*>(&Bs[k_b][n_b]) = bv;
        __syncthreads();
        #pragma unroll
        for (int kk = 0; kk < BK; ++kk) {
            float a[8], b[8];
            #pragma unroll
            for (int i = 0; i < 8; ++i) a[i] = As[kk][ty + 16 * i];
            #pragma unroll
            for (int j = 0; j < 8; ++j) b[j] = Bs[kk][tx + 16 * j];
            #pragma unroll
            for (int i = 0; i < 8; ++i)
                #pragma unroll
                for (int j = 0; j < 8; ++j) acc[i][j] = fmaf(a[i], b[j], acc[i][j]);
        }
        __syncthreads();
    }

    #pragma unroll
    for (int i = 0; i < 8; ++i) {
        int gm = bm + ty + 16 * i;
        if (gm >= M) continue;
        #pragma unroll
        for (int j = 0; j < 8; ++j) {
            int gn = bn + tx + 16 * j;
            float v = acc[i][j];
            if (BIAS) v += bias[gn];
            if (RELU) v = fmaxf(v, 0.f);
            C[(size_t)gm * N + gn] = v;
        }
    }
}

__global__ void pool_kernel(const float* __restrict__ A, const int* __restrict__ gstart,
                            float* __restrict__ pooled) {
    int g = blockIdx.x;      // 64 graphs
    int c = threadIdx.x;     // 128
    int s0 = gstart[g], s1 = gstart[g + 1];
    float s = 0.f;
    for (int i = s0; i < s1; ++i) s += A[(size_t)i * 128 + c];
    int cnt = s1 - s0;
    if (cnt < 1) cnt = 1;
    pooled[g * 128 + c] = s / (float)cnt;
}

__global__ void final_kernel(const float* __restrict__ pooled, const float* __restrict__ Wl,
                             const float* __restrict__ bl, float* __restrict__ out) {
    int t = threadIdx.x;   // 128 threads: g = t>>1, j = t&1
    int g = t >> 1, j = t & 1;
    float s = bl[j];
    #pragma unroll 4
    for (int c = 0; c < 128; ++c) s = fmaf(pooled[g * 128 + c], Wl[c * 2 + j], s);
    out[g * 2 + j] = s;
}

extern "C" void kernel_launch(void* const* d_in, const int* in_sizes, int n_in,
                              void* d_out, int out_size, void* d_ws, size_t ws_size,
                              hipStream_t stream) {
    const float* x   = (const float*)d_in[0];
    const int*   ei  = (const int*)d_in[1];
    const int*   bat = (const int*)d_in[2];
    const float* W1  = (const float*)d_in[3];
    const float* b1  = (const float*)d_in[4];
    const float* W2  = (const float*)d_in[5];
    const float* b2  = (const float*)d_in[6];
    const float* W3  = (const float*)d_in[7];
    const float* b3  = (const float*)d_in[8];
    const float* Wl  = (const float*)d_in[9];
    const float* bl  = (const float*)d_in[10];
    float* out = (float*)d_out;

    const int N = N_NODES_C;
    const int E = in_sizes[1] / 2;
    const int G = N_GRAPHS_C;

    const int* src = ei;
    const int* dst = ei + E;

    // workspace layout
    float* buf0    = (float*)d_ws;                       // 20000*512 f32
    float* buf1    = buf0 + (size_t)N * HID_C;           // 20000*512 f32
    int*   deg_cnt = (int*)(buf1 + (size_t)N * HID_C);   // N
    int*   row_ptr = deg_cnt + N;                        // N+1
    int*   cursor  = row_ptr + (N + 1);                  // N
    int*   col_idx = cursor + N;                         // E
    float* dinv    = (float*)(col_idx + E);              // N
    int*   gstart  = (int*)(dinv + N);                   // G+1
    float* pooled  = (float*)(gstart + (G + 4));         // G*128

    // --- build CSR (by dst) + dinv ---
    zero_int_kernel<<<(N + 255) / 256, 256, 0, stream>>>(deg_cnt, N);
    count_kernel<<<(E + 255) / 256, 256, 0, stream>>>(dst, deg_cnt, E);
    scan_kernel<<<1, 1024, 0, stream>>>(deg_cnt, row_ptr, cursor, dinv, N);
    fill_kernel<<<(E + 255) / 256, 256, 0, stream>>>(src, dst, cursor, col_idx, E);
    bounds_kernel<<<(N + 255) / 256, 256, 0, stream>>>(bat, N, G, gstart);

    const int MB = (N + 127) / 128;   // 157 row-blocks

    // --- layer 1: A0 = Ahat x  (F=128), then H1 = relu(A0 @ W1 + b1) ---
    agg_kernel<128, false, false><<<N, 128, 0, stream>>>(x, dinv, row_ptr, col_idx, nullptr, buf1, N);
    {
        dim3 grid(MB, HID_C / 128);
        gemm_kernel<128, 512, true, true><<<grid, 256, 0, stream>>>(buf1, W1, b1, buf0, N);
    }
    // --- layer 2: T2 = H1 @ W2, H2 = relu(Ahat T2 + b2) ---
    {
        dim3 grid(MB, 256 / 128);
        gemm_kernel<512, 256, false, false><<<grid, 256, 0, stream>>>(buf0, W2, nullptr, buf1, N);
    }
    agg_kernel<256, true, true><<<N, 256, 0, stream>>>(buf1, dinv, row_ptr, col_idx, b2, buf0, N);
    // --- layer 3: T3 = H2 @ W3, A3 = Ahat T3 + b3 ---
    {
        dim3 grid(MB, 1);
        gemm_kernel<256, 128, false, false><<<grid, 256, 0, stream>>>(buf0, W3, nullptr, buf1, N);
    }
    agg_kernel<128, true, false><<<N, 128, 0, stream>>>(buf1, dinv, row_ptr, col_idx, b3, buf0, N);

    // --- pool + final linear ---
    pool_kernel<<<G, 128, 0, stream>>>(buf0, gstart, pooled);
    final_kernel<<<1, 128, 0, stream>>>(pooled, Wl, bl, out);
}

// Round 2
// 398.846 us; speedup vs baseline: 1.4235x; 1.4235x over previous
//
#include <hip/hip_runtime.h>
#include <hip/hip_bf16.h>

// ---------------------------------------------------------------------------
// GCN: 3x gcn_conv + global_mean_pool + linear
//   h' = D^-1/2 (A+I) D^-1/2 (h W) + b
// Layer1 aggregates BEFORE GEMM ((AX)W == A(XW)), layers 2/3 after.
// GEMMs: bf16 MFMA with hi/lo split (3-term, ~f32 accuracy):
//   C = Ah*Bh + Al*Bh + Ah*Bl,  A split from f32 during LDS staging,
//   W pre-transposed+split to [N][K] bf16 planes.
// ---------------------------------------------------------------------------

#define N_NODES_C  20000
#define N_EDGES_C  320000
#define N_GRAPHS_C 64
#define F_IN_C     128
#define HID_C      512

typedef __attribute__((ext_vector_type(8))) short bf16x8;
typedef __attribute__((ext_vector_type(8))) unsigned short u16x8;
typedef __attribute__((ext_vector_type(4))) float f32x4;

static __device__ __forceinline__ unsigned short f2bf(float f) {
    __hip_bfloat16 h = __float2bfloat16(f);
    return *reinterpret_cast<unsigned short*>(&h);
}
static __device__ __forceinline__ float bf2f(unsigned short u) {
    __hip_bfloat16 h = *reinterpret_cast<__hip_bfloat16*>(&u);
    return __bfloat162float(h);
}

__global__ void zero_int_kernel(int* __restrict__ p, int n) {
    int i = blockIdx.x * blockDim.x + threadIdx.x;
    if (i < n) p[i] = 0;
}

__global__ void count_kernel(const int* __restrict__ dst, int* __restrict__ deg_cnt, int E) {
    int e = blockIdx.x * blockDim.x + threadIdx.x;
    if (e < E) atomicAdd(&deg_cnt[dst[e]], 1);
}

// Single-block exclusive scan over deg_cnt -> row_ptr (+cursor copy), dinv = rsqrt(cnt+1)
__global__ __launch_bounds__(1024) void scan_kernel(const int* __restrict__ deg_cnt,
                                                    int* __restrict__ row_ptr,
                                                    int* __restrict__ cursor,
                                                    float* __restrict__ dinv, int n) {
    __shared__ int sd[1024];
    int t = threadIdx.x;
    int carry = 0;
    for (int base = 0; base < n; base += 1024) {
        int idx = base + t;
        int v = (idx < n) ? deg_cnt[idx] : 0;
        sd[t] = v;
        __syncthreads();
        #pragma unroll
        for (int off = 1; off < 1024; off <<= 1) {
            int x = sd[t];
            if (t >= off) x += sd[t - off];
            __syncthreads();
            sd[t] = x;
            __syncthreads();
        }
        int incl = sd[t];
        int excl = incl - v;
        if (idx < n) {
            int rp = carry + excl;
            row_ptr[idx] = rp;
            cursor[idx]  = rp;
            dinv[idx]    = rsqrtf((float)(v + 1));  // +1 self-loop; deg always > 0
        }
        carry += sd[1023];
        __syncthreads();
    }
    if (t == 0) row_ptr[n] = carry;
}

__global__ void fill_kernel(const int* __restrict__ src, const int* __restrict__ dst,
                            int* __restrict__ cursor, int* __restrict__ col_idx, int E) {
    int e = blockIdx.x * blockDim.x + threadIdx.x;
    if (e >= E) return;
    int d = dst[e];
    int pos = atomicAdd(&cursor[d], 1);
    col_idx[pos] = src[e];
}

__global__ void bounds_kernel(const int* __restrict__ batch, int n, int ngraphs,
                              int* __restrict__ gstart) {
    int i = blockIdx.x * blockDim.x + threadIdx.x;
    if (i >= n) return;
    int b = batch[i];
    if (i == 0) {
        for (int g = 0; g <= b; ++g) gstart[g] = 0;
    } else {
        int bp = batch[i - 1];
        if (bp != b) for (int g = bp + 1; g <= b; ++g) gstart[g] = i;
    }
    if (i == n - 1) {
        for (int g = b + 1; g <= ngraphs; ++g) gstart[g] = n;
    }
}

// W [K][N] f32 -> WT_hi/WT_lo [N][K] bf16 split
__global__ void wconv_kernel(const float* __restrict__ W, unsigned short* __restrict__ WTh,
                             unsigned short* __restrict__ WTl, int Kd, int Nd) {
    int i = blockIdx.x * blockDim.x + threadIdx.x;
    if (i >= Kd * Nd) return;
    int k = i / Nd, n = i % Nd;
    float v = W[i];
    unsigned short hi = f2bf(v);
    unsigned short lo = f2bf(v - bf2f(hi));
    WTh[(size_t)n * Kd + k] = hi;
    WTl[(size_t)n * Kd + k] = lo;
}

// out[i] = dinv[i] * ( sum_{e in in(i)} h[src]*dinv[src] + dinv[i]*h[i] ) (+bias)(relu)
template <int F, bool BIAS, bool RELU>
__global__ void agg_kernel(const float* __restrict__ h, const float* __restrict__ dinv,
                           const int* __restrict__ row_ptr, const int* __restrict__ col_idx,
                           const float* __restrict__ bias, float* __restrict__ out, int n) {
    int i = blockIdx.x;
    int c = threadIdx.x;   // blockDim == F
    float di = dinv[i];
    float s = di * h[(size_t)i * F + c];   // self-loop term (pre-final-scale)
    int e0 = row_ptr[i], e1 = row_ptr[i + 1];
    for (int e = e0; e < e1; ++e) {
        int src = col_idx[e];
        s = fmaf(h[(size_t)src * F + c], dinv[src], s);
    }
    s *= di;
    if (BIAS) s += bias[c];
    if (RELU) s = fmaxf(s, 0.f);
    out[(size_t)i * F + c] = s;
}

// ---------------------------------------------------------------------------
// MFMA split-bf16 GEMM: C[M,N] = A[M,K] @ W[K,N] (+bias)(relu)
// A: f32 [M][K] (split to hi/lo bf16 during staging)
// W: pre-split WT_hi/WT_lo [N][K] bf16
// BM=128, BN (128 or 64), BK=64, 256 threads = 4 waves (2x2), wave tile 64x(BN/2).
// ---------------------------------------------------------------------------
template <int K, int N, int BN, bool BIAS, bool RELU>
__global__ __launch_bounds__(256) void gemm_mfma(const float* __restrict__ A,
                                                 const unsigned short* __restrict__ WTh,
                                                 const unsigned short* __restrict__ WTl,
                                                 const float* __restrict__ bias,
                                                 float* __restrict__ C, int M) {
    constexpr int BM = 128, BK = 64;
    constexpr int WN = BN / 2 / 16;           // n-frags per wave (4 for BN=128, 2 for BN=64)
    __shared__ unsigned short Ah[BM * BK];    // swizzled: idx = row*64 + (kc8 ^ ((row&7)<<3))
    __shared__ unsigned short Al[BM * BK];
    __shared__ unsigned short Bh[BN * BK];
    __shared__ unsigned short Bl[BN * BK];

    const int tid = threadIdx.x;
    const int wid = tid >> 6;
    const int lane16 = tid & 15;
    const int quad = (tid >> 4) & 3;
    const int wm = (wid >> 1) * 64;
    const int wn = (wid & 1) * (BN / 2);
    const int bm = blockIdx.x * BM;
    const int bn = blockIdx.y * BN;

    f32x4 acc[4][WN];
    #pragma unroll
    for (int mi = 0; mi < 4; ++mi)
        #pragma unroll
        for (int ni = 0; ni < WN; ++ni) acc[mi][ni] = (f32x4)(0.f);

    for (int kt = 0; kt < K / BK; ++kt) {
        // --- stage A: 128 rows x 8 chunks(16B) per plane; f32 -> hi/lo bf16 ---
        #pragma unroll
        for (int c = 0; c < 1024 / 256; ++c) {
            int ch = tid + c * 256;
            int row = ch >> 3, kc = ch & 7;
            int gm = bm + row;
            float v[8];
            if (gm < M) {
                const float* p = &A[(size_t)gm * K + kt * BK + kc * 8];
                f32x4 v0 = *reinterpret_cast<const f32x4*>(p);
                f32x4 v1 = *reinterpret_cast<const f32x4*>(p + 4);
                v[0]=v0.x; v[1]=v0.y; v[2]=v0.z; v[3]=v0.w;
                v[4]=v1.x; v[5]=v1.y; v[6]=v1.z; v[7]=v1.w;
            } else {
                #pragma unroll
                for (int j = 0; j < 8; ++j) v[j] = 0.f;
            }
            u16x8 hi, lo;
            #pragma unroll
            for (int j = 0; j < 8; ++j) {
                unsigned short h = f2bf(v[j]);
                hi[j] = h;
                lo[j] = f2bf(v[j] - bf2f(h));
            }
            int idx = row * 64 + ((kc * 8) ^ ((row & 7) << 3));
            *reinterpret_cast<u16x8*>(&Ah[idx]) = hi;
            *reinterpret_cast<u16x8*>(&Al[idx]) = lo;
        }
        // --- stage B: BN rows x 8 chunks per plane (already bf16) ---
        #pragma unroll
        for (int c = 0; c < (BN * 8) / 256; ++c) {
            int ch = tid + c * 256;
            int row = ch >> 3, kc = ch & 7;
            size_t goff = (size_t)(bn + row) * K + kt * BK + kc * 8;
            u16x8 vh = *reinterpret_cast<const u16x8*>(&WTh[goff]);
            u16x8 vl = *reinterpret_cast<const u16x8*>(&WTl[goff]);
            int idx = row * 64 + ((kc * 8) ^ ((row & 7) << 3));
            *reinterpret_cast<u16x8*>(&Bh[idx]) = vh;
            *reinterpret_cast<u16x8*>(&Bl[idx]) = vl;
        }
        __syncthreads();

        #pragma unroll
        for (int ks = 0; ks < 2; ++ks) {
            bf16x8 afh[4], afl[4], bfh[WN], bfl[WN];
            #pragma unroll
            for (int mi = 0; mi < 4; ++mi) {
                int row = wm + mi * 16 + lane16;
                int kidx = ks * 32 + quad * 8;
                int idx = row * 64 + (kidx ^ ((row & 7) << 3));
                afh[mi] = *reinterpret_cast<bf16x8*>(&Ah[idx]);
                afl[mi] = *reinterpret_cast<bf16x8*>(&Al[idx]);
            }
            #pragma unroll
            for (int ni = 0; ni < WN; ++ni) {
                int row = wn + ni * 16 + lane16;
                int kidx = ks * 32 + quad * 8;
                int idx = row * 64 + (kidx ^ ((row & 7) << 3));
                bfh[ni] = *reinterpret_cast<bf16x8*>(&Bh[idx]);
                bfl[ni] = *reinterpret_cast<bf16x8*>(&Bl[idx]);
            }
            #pragma unroll
            for (int mi = 0; mi < 4; ++mi)
                #pragma unroll
                for (int ni = 0; ni < WN; ++ni) {
                    acc[mi][ni] = __builtin_amdgcn_mfma_f32_16x16x32_bf16(afh[mi], bfh[ni], acc[mi][ni], 0, 0, 0);
                    acc[mi][ni] = __builtin_amdgcn_mfma_f32_16x16x32_bf16(afl[mi], bfh[ni], acc[mi][ni], 0, 0, 0);
                    acc[mi][ni] = __builtin_amdgcn_mfma_f32_16x16x32_bf16(afh[mi], bfl[ni], acc[mi][ni], 0, 0, 0);
                }
        }
        __syncthreads();
    }

    // epilogue: D row = (lane>>4)*4 + r, col = lane&15
    #pragma unroll
    for (int mi = 0; mi < 4; ++mi) {
        #pragma unroll
        for (int r = 0; r < 4; ++r) {
            int gm = bm + wm + mi * 16 + quad * 4 + r;
            if (gm >= M) continue;
            #pragma unroll
            for (int ni = 0; ni < WN; ++ni) {
                int gn = bn + wn + ni * 16 + lane16;
                float v = acc[mi][ni][r];
                if (BIAS) v += bias[gn];
                if (RELU) v = fmaxf(v, 0.f);
                C[(size_t)gm * N + gn] = v;
            }
        }
    }
}

__global__ void pool_kernel(const float* __restrict__ A, const int* __restrict__ gstart,
                            float* __restrict__ pooled) {
    int g = blockIdx.x;      // 64 graphs
    int c = threadIdx.x;     // 128
    int s0 = gstart[g], s1 = gstart[g + 1];
    float s = 0.f;
    for (int i = s0; i < s1; ++i) s += A[(size_t)i * 128 + c];
    int cnt = s1 - s0;
    if (cnt < 1) cnt = 1;
    pooled[g * 128 + c] = s / (float)cnt;
}

__global__ void final_kernel(const float* __restrict__ pooled, const float* __restrict__ Wl,
                             const float* __restrict__ bl, float* __restrict__ out) {
    int t = threadIdx.x;   // 128 threads: g = t>>1, j = t&1
    int g = t >> 1, j = t & 1;
    float s = bl[j];
    #pragma unroll 4
    for (int c = 0; c < 128; ++c) s = fmaf(pooled[g * 128 + c], Wl[c * 2 + j], s);
    out[g * 2 + j] = s;
}

extern "C" void kernel_launch(void* const* d_in, const int* in_sizes, int n_in,
                              void* d_out, int out_size, void* d_ws, size_t ws_size,
                              hipStream_t stream) {
    const float* x   = (const float*)d_in[0];
    const int*   ei  = (const int*)d_in[1];
    const int*   bat = (const int*)d_in[2];
    const float* W1  = (const float*)d_in[3];
    const float* b1  = (const float*)d_in[4];
    const float* W2  = (const float*)d_in[5];
    const float* b2  = (const float*)d_in[6];
    const float* W3  = (const float*)d_in[7];
    const float* b3  = (const float*)d_in[8];
    const float* Wl  = (const float*)d_in[9];
    const float* bl  = (const float*)d_in[10];
    float* out = (float*)d_out;

    const int N = N_NODES_C;
    const int E = in_sizes[1] / 2;
    const int G = N_GRAPHS_C;

    const int* src = ei;
    const int* dst = ei + E;

    // workspace layout
    float* buf0    = (float*)d_ws;                       // 20000*512 f32
    float* buf1    = buf0 + (size_t)N * HID_C;           // 20000*512 f32
    int*   deg_cnt = (int*)(buf1 + (size_t)N * HID_C);   // N
    int*   row_ptr = deg_cnt + N;                        // N+1
    int*   cursor  = row_ptr + (N + 1);                  // N
    int*   col_idx = cursor + N;                         // E
    float* dinv    = (float*)(col_idx + E);              // N
    int*   gstart  = (int*)(dinv + N);                   // G+1
    float* pooled  = (float*)(gstart + (G + 4));         // G*128
    // weight planes (16B aligned)
    uintptr_t wp = (uintptr_t)(pooled + G * 128);
    wp = (wp + 15) & ~(uintptr_t)15;
    unsigned short* W1Th = (unsigned short*)wp;          // 512*128
    unsigned short* W1Tl = W1Th + 512 * 128;
    unsigned short* W2Th = W1Tl + 512 * 128;             // 256*512
    unsigned short* W2Tl = W2Th + 256 * 512;
    unsigned short* W3Th = W2Tl + 256 * 512;             // 128*256
    unsigned short* W3Tl = W3Th + 128 * 256;

    // --- build CSR (by dst) + dinv + weight conversion ---
    zero_int_kernel<<<(N + 255) / 256, 256, 0, stream>>>(deg_cnt, N);
    count_kernel<<<(E + 255) / 256, 256, 0, stream>>>(dst, deg_cnt, E);
    scan_kernel<<<1, 1024, 0, stream>>>(deg_cnt, row_ptr, cursor, dinv, N);
    fill_kernel<<<(E + 255) / 256, 256, 0, stream>>>(src, dst, cursor, col_idx, E);
    bounds_kernel<<<(N + 255) / 256, 256, 0, stream>>>(bat, N, G, gstart);
    wconv_kernel<<<(128 * 512 + 255) / 256, 256, 0, stream>>>(W1, W1Th, W1Tl, 128, 512);
    wconv_kernel<<<(512 * 256 + 255) / 256, 256, 0, stream>>>(W2, W2Th, W2Tl, 512, 256);
    wconv_kernel<<<(256 * 128 + 255) / 256, 256, 0, stream>>>(W3, W3Th, W3Tl, 256, 128);

    const int MB = (N + 127) / 128;   // 157 row-blocks

    // --- layer 1: A0 = Ahat x (F=128), then H1 = relu(A0 @ W1 + b1) ---
    agg_kernel<128, false, false><<<N, 128, 0, stream>>>(x, dinv, row_ptr, col_idx, nullptr, buf1, N);
    {
        dim3 grid(MB, 512 / 128);
        gemm_mfma<128, 512, 128, true, true><<<grid, 256, 0, stream>>>(buf1, W1Th, W1Tl, b1, buf0, N);
    }
    // --- layer 2: T2 = H1 @ W2, H2 = relu(Ahat T2 + b2) ---
    {
        dim3 grid(MB, 256 / 128);
        gemm_mfma<512, 256, 128, false, false><<<grid, 256, 0, stream>>>(buf0, W2Th, W2Tl, nullptr, buf1, N);
    }
    agg_kernel<256, true, true><<<N, 256, 0, stream>>>(buf1, dinv, row_ptr, col_idx, b2, buf0, N);
    // --- layer 3: T3 = H2 @ W3, A3 = Ahat T3 + b3 ---
    {
        dim3 grid(MB, 128 / 64);
        gemm_mfma<256, 128, 64, false, false><<<grid, 256, 0, stream>>>(buf0, W3Th, W3Tl, nullptr, buf1, N);
    }
    agg_kernel<128, true, false><<<N, 128, 0, stream>>>(buf1, dinv, row_ptr, col_idx, b3, buf0, N);

    // --- pool + final linear ---
    pool_kernel<<<G, 128, 0, stream>>>(buf0, gstart, pooled);
    final_kernel<<<1, 128, 0, stream>>>(pooled, Wl, bl, out);
}

// Round 3
// 282.332 us; speedup vs baseline: 2.0110x; 1.4127x over previous
//
#include <hip/hip_runtime.h>
#include <hip/hip_bf16.h>

// ---------------------------------------------------------------------------
// GCN: 3x gcn_conv + global_mean_pool + linear
//   h' = D^-1/2 (A+I) D^-1/2 (h W) + b
// Layer1 aggregates BEFORE GEMM ((AX)W == A(XW)), layers 2/3 after.
// All node-feature buffers bf16 (halves gather traffic); accumulation f32.
// GEMMs: bf16 MFMA, A single-plane bf16, W pre-transposed hi/lo split:
//   C = A@Wh + A@Wl  (removes weight quantization error).
// Pool: two-stage deterministic parallel reduction (64x8 blocks).
// ---------------------------------------------------------------------------

#define N_NODES_C  20000
#define N_EDGES_C  320000
#define N_GRAPHS_C 64
#define HID_C      512

typedef __attribute__((ext_vector_type(8))) short bf16x8;
typedef __attribute__((ext_vector_type(8))) unsigned short u16x8;
typedef __attribute__((ext_vector_type(4))) float f32x4;

static __device__ __forceinline__ unsigned short f2bf(float f) {
    __hip_bfloat16 h = __float2bfloat16(f);
    return *reinterpret_cast<unsigned short*>(&h);
}
static __device__ __forceinline__ float bf2f(unsigned short u) {
    __hip_bfloat16 h = *reinterpret_cast<__hip_bfloat16*>(&u);
    return __bfloat162float(h);
}

__global__ void count_kernel(const int* __restrict__ dst, int* __restrict__ deg_cnt, int E) {
    int e = blockIdx.x * blockDim.x + threadIdx.x;
    if (e < E) atomicAdd(&deg_cnt[dst[e]], 1);
}

// Single-block scan via wave shfl: row_ptr/cursor = exclusive prefix, dinv = rsqrt(cnt+1)
__global__ __launch_bounds__(1024) void scan_kernel(const int* __restrict__ deg_cnt,
                                                    int* __restrict__ row_ptr,
                                                    int* __restrict__ cursor,
                                                    float* __restrict__ dinv, int n) {
    __shared__ int ws[16];
    int t = threadIdx.x;
    int wid = t >> 6, lane = t & 63;
    int carry = 0;
    for (int base = 0; base < n; base += 1024) {
        int idx = base + t;
        int v = (idx < n) ? deg_cnt[idx] : 0;
        int x = v;
        #pragma unroll
        for (int off = 1; off < 64; off <<= 1) {
            int y = __shfl_up(x, off);
            if (lane >= off) x += y;
        }
        if (lane == 63) ws[wid] = x;
        __syncthreads();
        if (wid == 0 && lane < 16) {
            int w = ws[lane];
            #pragma unroll
            for (int off = 1; off < 16; off <<= 1) {
                int y = __shfl_up(w, off);
                if (lane >= off) w += y;
            }
            ws[lane] = w;  // inclusive wave-sum prefix
        }
        __syncthreads();
        int wave_excl = (wid == 0) ? 0 : ws[wid - 1];
        int total = ws[15];
        if (idx < n) {
            int rp = carry + wave_excl + (x - v);
            row_ptr[idx] = rp;
            cursor[idx]  = rp;
            dinv[idx]    = rsqrtf((float)(v + 1));  // +1 self-loop; deg > 0 always
        }
        carry += total;
        __syncthreads();
    }
    if (t == 0) row_ptr[n] = carry;
}

__global__ void fill_kernel(const int* __restrict__ src, const int* __restrict__ dst,
                            int* __restrict__ cursor, int* __restrict__ col_idx, int E) {
    int e = blockIdx.x * blockDim.x + threadIdx.x;
    if (e >= E) return;
    int d = dst[e];
    int pos = atomicAdd(&cursor[d], 1);
    col_idx[pos] = src[e];
}

__global__ void bounds_kernel(const int* __restrict__ batch, int n, int ngraphs,
                              int* __restrict__ gstart) {
    int i = blockIdx.x * blockDim.x + threadIdx.x;
    if (i >= n) return;
    int b = batch[i];
    if (i == 0) {
        for (int g = 0; g <= b; ++g) gstart[g] = 0;
    } else {
        int bp = batch[i - 1];
        if (bp != b) for (int g = bp + 1; g <= b; ++g) gstart[g] = i;
    }
    if (i == n - 1) {
        for (int g = b + 1; g <= ngraphs; ++g) gstart[g] = n;
    }
}

// W [K][N] f32 -> WT_hi/WT_lo [N][K] bf16 split
__global__ void wconv_kernel(const float* __restrict__ W, unsigned short* __restrict__ WTh,
                             unsigned short* __restrict__ WTl, int Kd, int Nd) {
    int i = blockIdx.x * blockDim.x + threadIdx.x;
    if (i >= Kd * Nd) return;
    int k = i / Nd, n = i % Nd;
    float v = W[i];
    unsigned short hi = f2bf(v);
    unsigned short lo = f2bf(v - bf2f(hi));
    WTh[(size_t)n * Kd + k] = hi;
    WTl[(size_t)n * Kd + k] = lo;
}

// x f32 -> bf16
__global__ void xconv_kernel(const float* __restrict__ x, unsigned short* __restrict__ xb, int n) {
    int i = blockIdx.x * blockDim.x + threadIdx.x;
    if (i >= n / 4) return;
    f32x4 v = *reinterpret_cast<const f32x4*>(&x[i * 4]);
    ushort4 o;
    o.x = f2bf(v.x); o.y = f2bf(v.y); o.z = f2bf(v.z); o.w = f2bf(v.w);
    *reinterpret_cast<ushort4*>(&xb[i * 4]) = o;
}

// out[i] = dinv[i]*( sum_{e in(i)} h[src]*dinv[src] + dinv[i]*h[i] ) (+bias)(relu), bf16 in/out
template <int F, bool BIAS, bool RELU>
__global__ void agg_kernel(const unsigned short* __restrict__ h, const float* __restrict__ dinv,
                           const int* __restrict__ row_ptr, const int* __restrict__ col_idx,
                           const float* __restrict__ bias, unsigned short* __restrict__ out, int n) {
    int i = blockIdx.x;
    int c = threadIdx.x;   // blockDim == F
    float di = dinv[i];
    float s = di * bf2f(h[(size_t)i * F + c]);   // self-loop term
    int e0 = row_ptr[i], e1 = row_ptr[i + 1];
    for (int e = e0; e < e1; ++e) {
        int src = col_idx[e];
        s = fmaf(bf2f(h[(size_t)src * F + c]), dinv[src], s);
    }
    s *= di;
    if (BIAS) s += bias[c];
    if (RELU) s = fmaxf(s, 0.f);
    out[(size_t)i * F + c] = f2bf(s);
}

// ---------------------------------------------------------------------------
// MFMA bf16 GEMM: C[M,N] = A[M,K] @ W[K,N] (+bias)(relu), A bf16, W hi/lo bf16,
// C bf16. BM=128, BN in {128,64}, BK=64, 256 threads = 4 waves (2x2).
// LDS XOR-swizzled (T2): idx = row*64 + (k ^ ((row&7)<<3)), ushort units.
// ---------------------------------------------------------------------------
template <int K, int N, int BN, bool BIAS, bool RELU>
__global__ __launch_bounds__(256) void gemm_mfma(const unsigned short* __restrict__ A,
                                                 const unsigned short* __restrict__ WTh,
                                                 const unsigned short* __restrict__ WTl,
                                                 const float* __restrict__ bias,
                                                 unsigned short* __restrict__ C, int M) {
    constexpr int BM = 128, BK = 64;
    constexpr int WN = BN / 2 / 16;           // n-frags/wave: 4 (BN=128) or 2 (BN=64)
    __shared__ unsigned short As[BM * BK];
    __shared__ unsigned short Bh[BN * BK];
    __shared__ unsigned short Bl[BN * BK];

    const int tid = threadIdx.x;
    const int wid = tid >> 6;
    const int lane16 = tid & 15;
    const int quad = (tid >> 4) & 3;
    const int wm = (wid >> 1) * 64;
    const int wn = (wid & 1) * (BN / 2);
    const int bm = blockIdx.x * BM;
    const int bn = blockIdx.y * BN;

    f32x4 acc[4][WN];
    #pragma unroll
    for (int mi = 0; mi < 4; ++mi)
        #pragma unroll
        for (int ni = 0; ni < WN; ++ni) acc[mi][ni] = (f32x4)(0.f);

    for (int kt = 0; kt < K / BK; ++kt) {
        // --- stage A: BM rows x 8 chunks of 16B (8 bf16) ---
        #pragma unroll
        for (int c = 0; c < (BM * 8) / 256; ++c) {
            int ch = tid + c * 256;
            int row = ch >> 3, kc = ch & 7;
            int gm = bm + row;
            u16x8 av = (u16x8)(0);
            if (gm < M) av = *reinterpret_cast<const u16x8*>(&A[(size_t)gm * K + kt * BK + kc * 8]);
            *reinterpret_cast<u16x8*>(&As[row * 64 + ((kc * 8) ^ ((row & 7) << 3))]) = av;
        }
        // --- stage B: 2 planes x BN rows x 8 chunks ---
        #pragma unroll
        for (int c = 0; c < (2 * BN * 8) / 256; ++c) {
            int ch = tid + c * 256;
            int plane = ch / (BN * 8);
            int r2 = ch % (BN * 8);
            int row = r2 >> 3, kc = r2 & 7;
            const unsigned short* srcp = plane ? WTl : WTh;
            unsigned short* dstp = plane ? Bl : Bh;
            u16x8 bv = *reinterpret_cast<const u16x8*>(&srcp[(size_t)(bn + row) * K + kt * BK + kc * 8]);
            *reinterpret_cast<u16x8*>(&dstp[row * 64 + ((kc * 8) ^ ((row & 7) << 3))]) = bv;
        }
        __syncthreads();

        #pragma unroll
        for (int ks = 0; ks < 2; ++ks) {
            bf16x8 af[4], bfh[WN], bfl[WN];
            #pragma unroll
            for (int mi = 0; mi < 4; ++mi) {
                int row = wm + mi * 16 + lane16;
                int kidx = ks * 32 + quad * 8;
                af[mi] = *reinterpret_cast<bf16x8*>(&As[row * 64 + (kidx ^ ((row & 7) << 3))]);
            }
            #pragma unroll
            for (int ni = 0; ni < WN; ++ni) {
                int row = wn + ni * 16 + lane16;
                int kidx = ks * 32 + quad * 8;
                bfh[ni] = *reinterpret_cast<bf16x8*>(&Bh[row * 64 + (kidx ^ ((row & 7) << 3))]);
                bfl[ni] = *reinterpret_cast<bf16x8*>(&Bl[row * 64 + (kidx ^ ((row & 7) << 3))]);
            }
            #pragma unroll
            for (int mi = 0; mi < 4; ++mi)
                #pragma unroll
                for (int ni = 0; ni < WN; ++ni) {
                    acc[mi][ni] = __builtin_amdgcn_mfma_f32_16x16x32_bf16(af[mi], bfh[ni], acc[mi][ni], 0, 0, 0);
                    acc[mi][ni] = __builtin_amdgcn_mfma_f32_16x16x32_bf16(af[mi], bfl[ni], acc[mi][ni], 0, 0, 0);
                }
        }
        __syncthreads();
    }

    // epilogue: D row = quad*4 + r, col = lane16
    #pragma unroll
    for (int mi = 0; mi < 4; ++mi) {
        #pragma unroll
        for (int r = 0; r < 4; ++r) {
            int gm = bm + wm + mi * 16 + quad * 4 + r;
            if (gm >= M) continue;
            #pragma unroll
            for (int ni = 0; ni < WN; ++ni) {
                int gn = bn + wn + ni * 16 + lane16;
                float v = acc[mi][ni][r];
                if (BIAS) v += bias[gn];
                if (RELU) v = fmaxf(v, 0.f);
                C[(size_t)gm * N + gn] = f2bf(v);
            }
        }
    }
}

// pool stage 1: grid (G, 8), 256 threads = 2 rows x 128 cols, rows strided by 16
__global__ void pool_partial_kernel(const unsigned short* __restrict__ A,
                                    const int* __restrict__ gstart,
                                    float* __restrict__ partial) {
    __shared__ float sd[256];
    int g = blockIdx.x, y = blockIdx.y;
    int t = threadIdx.x;
    int c = t & 127, r = t >> 7;
    int s0 = gstart[g], s1 = gstart[g + 1];
    float s = 0.f;
    for (int i = s0 + y * 2 + r; i < s1; i += 16)
        s += bf2f(A[(size_t)i * 128 + c]);
    sd[t] = s;
    __syncthreads();
    if (t < 128) partial[(size_t)(g * 8 + y) * 128 + c] = sd[t] + sd[t + 128];
}

// pool stage 2: 64 blocks x 128 threads; sum 8 partials, divide by count
__global__ void pool_reduce_kernel(const float* __restrict__ partial,
                                   const int* __restrict__ gstart,
                                   float* __restrict__ pooled) {
    int g = blockIdx.x, c = threadIdx.x;
    float s = 0.f;
    #pragma unroll
    for (int y = 0; y < 8; ++y) s += partial[(size_t)(g * 8 + y) * 128 + c];
    int cnt = gstart[g + 1] - gstart[g];
    if (cnt < 1) cnt = 1;
    pooled[g * 128 + c] = s / (float)cnt;
}

__global__ void final_kernel(const float* __restrict__ pooled, const float* __restrict__ Wl,
                             const float* __restrict__ bl, float* __restrict__ out) {
    int t = threadIdx.x;   // 128 threads: g = t>>1, j = t&1
    int g = t >> 1, j = t & 1;
    float s = bl[j];
    #pragma unroll 4
    for (int c = 0; c < 128; ++c) s = fmaf(pooled[g * 128 + c], Wl[c * 2 + j], s);
    out[g * 2 + j] = s;
}

extern "C" void kernel_launch(void* const* d_in, const int* in_sizes, int n_in,
                              void* d_out, int out_size, void* d_ws, size_t ws_size,
                              hipStream_t stream) {
    const float* x   = (const float*)d_in[0];
    const int*   ei  = (const int*)d_in[1];
    const int*   bat = (const int*)d_in[2];
    const float* W1  = (const float*)d_in[3];
    const float* b1  = (const float*)d_in[4];
    const float* W2  = (const float*)d_in[5];
    const float* b2  = (const float*)d_in[6];
    const float* W3  = (const float*)d_in[7];
    const float* b3  = (const float*)d_in[8];
    const float* Wl  = (const float*)d_in[9];
    const float* bl  = (const float*)d_in[10];
    float* out = (float*)d_out;

    const int N = N_NODES_C;
    const int E = in_sizes[1] / 2;
    const int G = N_GRAPHS_C;

    const int* src = ei;
    const int* dst = ei + E;

    // -------- workspace layout (all 16B-aligned carving) --------
    unsigned short* xb  = (unsigned short*)d_ws;         // N*128 bf16
    unsigned short* A1b = xb  + (size_t)N * 128;         // N*128
    unsigned short* H1  = A1b + (size_t)N * 128;         // N*512
    unsigned short* T2  = H1  + (size_t)N * 512;         // N*256
    unsigned short* H2  = T2  + (size_t)N * 256;         // N*256
    unsigned short* T3  = H2  + (size_t)N * 256;         // N*128
    unsigned short* A3  = T3  + (size_t)N * 128;         // N*128
    unsigned short* W1Th = A3 + (size_t)N * 128;         // 512*128
    unsigned short* W1Tl = W1Th + 512 * 128;
    unsigned short* W2Th = W1Tl + 512 * 128;             // 256*512
    unsigned short* W2Tl = W2Th + 256 * 512;
    unsigned short* W3Th = W2Tl + 256 * 512;             // 128*256
    unsigned short* W3Tl = W3Th + 128 * 256;
    int*   deg_cnt = (int*)(W3Tl + 128 * 256);           // N
    int*   row_ptr = deg_cnt + N;                        // N+1
    int*   cursor  = row_ptr + (N + 1);                  // N
    int*   col_idx = cursor + N;                         // E
    float* dinv    = (float*)(col_idx + E);              // N
    int*   gstart  = (int*)(dinv + N);                   // G+1 (+pad)
    float* partial = (float*)(gstart + (G + 4));         // G*8*128
    float* pooled  = partial + (size_t)G * 8 * 128;      // G*128

    // --- build CSR (by dst) + dinv + weight/x conversion ---
    hipMemsetAsync(deg_cnt, 0, N * sizeof(int), stream);
    count_kernel<<<(E + 255) / 256, 256, 0, stream>>>(dst, deg_cnt, E);
    scan_kernel<<<1, 1024, 0, stream>>>(deg_cnt, row_ptr, cursor, dinv, N);
    fill_kernel<<<(E + 255) / 256, 256, 0, stream>>>(src, dst, cursor, col_idx, E);
    bounds_kernel<<<(N + 255) / 256, 256, 0, stream>>>(bat, N, G, gstart);
    wconv_kernel<<<(128 * 512 + 255) / 256, 256, 0, stream>>>(W1, W1Th, W1Tl, 128, 512);
    wconv_kernel<<<(512 * 256 + 255) / 256, 256, 0, stream>>>(W2, W2Th, W2Tl, 512, 256);
    wconv_kernel<<<(256 * 128 + 255) / 256, 256, 0, stream>>>(W3, W3Th, W3Tl, 256, 128);
    xconv_kernel<<<((N * 128 / 4) + 255) / 256, 256, 0, stream>>>(x, xb, N * 128);

    const int MB = (N + 127) / 128;   // 157 row-blocks

    // --- layer 1: A1 = Ahat xb (F=128), H1 = relu(A1 @ W1 + b1) ---
    agg_kernel<128, false, false><<<N, 128, 0, stream>>>(xb, dinv, row_ptr, col_idx, nullptr, A1b, N);
    {
        dim3 grid(MB, 512 / 128);
        gemm_mfma<128, 512, 128, true, true><<<grid, 256, 0, stream>>>(A1b, W1Th, W1Tl, b1, H1, N);
    }
    // --- layer 2: T2 = H1 @ W2, H2 = relu(Ahat T2 + b2) ---
    {
        dim3 grid(MB, 256 / 128);
        gemm_mfma<512, 256, 128, false, false><<<grid, 256, 0, stream>>>(H1, W2Th, W2Tl, nullptr, T2, N);
    }
    agg_kernel<256, true, true><<<N, 256, 0, stream>>>(T2, dinv, row_ptr, col_idx, b2, H2, N);
    // --- layer 3: T3 = H2 @ W3, A3 = Ahat T3 + b3 ---
    {
        dim3 grid(MB, 128 / 64);
        gemm_mfma<256, 128, 64, false, false><<<grid, 256, 0, stream>>>(H2, W3Th, W3Tl, nullptr, T3, N);
    }
    agg_kernel<128, true, false><<<N, 128, 0, stream>>>(T3, dinv, row_ptr, col_idx, b3, A3, N);

    // --- pool (two-stage) + final linear ---
    {
        dim3 grid(G, 8);
        pool_partial_kernel<<<grid, 256, 0, stream>>>(A3, gstart, partial);
    }
    pool_reduce_kernel<<<G, 128, 0, stream>>>(partial, gstart, pooled);
    final_kernel<<<1, 128, 0, stream>>>(pooled, Wl, bl, out);
}

// Round 4
// 217.424 us; speedup vs baseline: 2.6114x; 1.2985x over previous
//
#include <hip/hip_runtime.h>
#include <hip/hip_bf16.h>

// ---------------------------------------------------------------------------
// GCN: 3x gcn_conv + global_mean_pool + linear
//   h' = D^-1/2 (A+I) D^-1/2 (h W) + b
// Layer1 aggregates BEFORE GEMM ((AX)W == A(XW)), layers 2/3 after.
// dinv is FOLDED into stored features (GEMM epilogue / xconv write h*dinv),
// so aggregation is a pure gather+sum: out[i] = dinv[i]*(hs[i] + sum hs[src]).
// Aggregation: 1 block/node, 4 waves, wave-wide row gathers (VEC bf16/lane),
// edge indices broadcast via shfl, unroll-4 for MLP.
// GEMMs: bf16 MFMA, W pre-transposed hi/lo split (C = A@Wh + A@Wl).
// ---------------------------------------------------------------------------

#define N_NODES_C  20000
#define N_GRAPHS_C 64
#define HID_C      512

typedef __attribute__((ext_vector_type(8))) short bf16x8;
typedef __attribute__((ext_vector_type(8))) unsigned short u16x8;
typedef __attribute__((ext_vector_type(4))) float f32x4;

static __device__ __forceinline__ unsigned short f2bf(float f) {
    __hip_bfloat16 h = __float2bfloat16(f);
    return *reinterpret_cast<unsigned short*>(&h);
}
static __device__ __forceinline__ float bf2f(unsigned short u) {
    __hip_bfloat16 h = *reinterpret_cast<__hip_bfloat16*>(&u);
    return __bfloat162float(h);
}
static __device__ __forceinline__ float bfu_lo(unsigned u) {
    union { unsigned x; float f; } t; t.x = u << 16; return t.f;
}
static __device__ __forceinline__ float bfu_hi(unsigned u) {
    union { unsigned x; float f; } t; t.x = u & 0xffff0000u; return t.f;
}

__global__ void count_kernel(const int* __restrict__ dst, int* __restrict__ deg_cnt, int E) {
    int e = blockIdx.x * blockDim.x + threadIdx.x;
    if (e < E) atomicAdd(&deg_cnt[dst[e]], 1);
}

// Single-block scan via wave shfl: row_ptr/cursor = exclusive prefix, dinv = rsqrt(cnt+1)
__global__ __launch_bounds__(1024) void scan_kernel(const int* __restrict__ deg_cnt,
                                                    int* __restrict__ row_ptr,
                                                    int* __restrict__ cursor,
                                                    float* __restrict__ dinv, int n) {
    __shared__ int ws[16];
    int t = threadIdx.x;
    int wid = t >> 6, lane = t & 63;
    int carry = 0;
    for (int base = 0; base < n; base += 1024) {
        int idx = base + t;
        int v = (idx < n) ? deg_cnt[idx] : 0;
        int x = v;
        #pragma unroll
        for (int off = 1; off < 64; off <<= 1) {
            int y = __shfl_up(x, off);
            if (lane >= off) x += y;
        }
        if (lane == 63) ws[wid] = x;
        __syncthreads();
        if (wid == 0 && lane < 16) {
            int w = ws[lane];
            #pragma unroll
            for (int off = 1; off < 16; off <<= 1) {
                int y = __shfl_up(w, off);
                if (lane >= off) w += y;
            }
            ws[lane] = w;
        }
        __syncthreads();
        int wave_excl = (wid == 0) ? 0 : ws[wid - 1];
        int total = ws[15];
        if (idx < n) {
            int rp = carry + wave_excl + (x - v);
            row_ptr[idx] = rp;
            cursor[idx]  = rp;
            dinv[idx]    = rsqrtf((float)(v + 1));
        }
        carry += total;
        __syncthreads();
    }
    if (t == 0) row_ptr[n] = carry;
}

__global__ void fill_kernel(const int* __restrict__ src, const int* __restrict__ dst,
                            int* __restrict__ cursor, int* __restrict__ col_idx, int E) {
    int e = blockIdx.x * blockDim.x + threadIdx.x;
    if (e >= E) return;
    int d = dst[e];
    int pos = atomicAdd(&cursor[d], 1);
    col_idx[pos] = src[e];
}

__global__ void bounds_kernel(const int* __restrict__ batch, int n, int ngraphs,
                              int* __restrict__ gstart) {
    int i = blockIdx.x * blockDim.x + threadIdx.x;
    if (i >= n) return;
    int b = batch[i];
    if (i == 0) {
        for (int g = 0; g <= b; ++g) gstart[g] = 0;
    } else {
        int bp = batch[i - 1];
        if (bp != b) for (int g = bp + 1; g <= b; ++g) gstart[g] = i;
    }
    if (i == n - 1) {
        for (int g = b + 1; g <= ngraphs; ++g) gstart[g] = n;
    }
}

// W [K][N] f32 -> WT_hi/WT_lo [N][K] bf16 split
__global__ void wconv_kernel(const float* __restrict__ W, unsigned short* __restrict__ WTh,
                             unsigned short* __restrict__ WTl, int Kd, int Nd) {
    int i = blockIdx.x * blockDim.x + threadIdx.x;
    if (i >= Kd * Nd) return;
    int k = i / Nd, n = i % Nd;
    float v = W[i];
    unsigned short hi = f2bf(v);
    unsigned short lo = f2bf(v - bf2f(hi));
    WTh[(size_t)n * Kd + k] = hi;
    WTl[(size_t)n * Kd + k] = lo;
}

// xs[i] = bf16(x[i] * dinv[row]); 32 threads/row (128 cols / 4)
__global__ void xconv_kernel(const float* __restrict__ x, const float* __restrict__ dinv,
                             unsigned short* __restrict__ xs, int nrows) {
    int t = blockIdx.x * blockDim.x + threadIdx.x;
    int row = t >> 5, q = t & 31;
    if (row >= nrows) return;
    float di = dinv[row];
    f32x4 v = *reinterpret_cast<const f32x4*>(&x[(size_t)row * 128 + q * 4]);
    ushort4 o;
    o.x = f2bf(v.x * di); o.y = f2bf(v.y * di);
    o.z = f2bf(v.z * di); o.w = f2bf(v.w * di);
    *reinterpret_cast<ushort4*>(&xs[(size_t)row * 128 + q * 4]) = o;
}

// ---------------------------------------------------------------------------
// Aggregation: out[i] = dinv[i]*(hs[i] + sum_{e in(i)} hs[src]) (+bias)(relu)
// hs is pre-scaled by dinv. 1 block/node, 4 waves; each wave gathers whole
// rows (VEC=F/64 bf16 per lane) for its contiguous edge chunk; shfl-broadcast
// indices; unroll-4 independent gathers; LDS cross-wave reduce.
// ---------------------------------------------------------------------------
template <int F, bool BIAS, bool RELU>
__global__ __launch_bounds__(256) void agg_kernel(const unsigned short* __restrict__ hs,
                                                  const float* __restrict__ dinv,
                                                  const int* __restrict__ row_ptr,
                                                  const int* __restrict__ col_idx,
                                                  const float* __restrict__ bias,
                                                  unsigned short* __restrict__ out, int n) {
    constexpr int VEC = F / 64;         // bf16 per lane: 2 (F=128) or 4 (F=256)
    __shared__ float red[3 * F];
    int i = blockIdx.x;
    int tid = threadIdx.x;
    int wid = tid >> 6, lane = tid & 63;
    int e0 = row_ptr[i], e1 = row_ptr[i + 1];
    int deg = e1 - e0;

    float acc[VEC];
    #pragma unroll
    for (int v = 0; v < VEC; ++v) acc[v] = 0.f;

    // wave 0 seeds with the self row
    if (wid == 0) {
        if constexpr (VEC == 2) {
            unsigned u = *reinterpret_cast<const unsigned*>(&hs[(size_t)i * F + lane * 2]);
            acc[0] = bfu_lo(u); acc[1] = bfu_hi(u);
        } else {
            uint2 u = *reinterpret_cast<const uint2*>(&hs[(size_t)i * F + lane * 4]);
            acc[0] = bfu_lo(u.x); acc[1] = bfu_hi(u.x);
            acc[2] = bfu_lo(u.y); acc[3] = bfu_hi(u.y);
        }
    }

    // contiguous edge chunk per wave
    int per = (deg + 3) >> 2;
    int cs = e0 + wid * per;
    int ce = cs + per; if (ce > e1) ce = e1;
    for (int base = cs; base < ce; base += 64) {
        int rem = ce - base;
        int mm = rem < 64 ? rem : 64;
        int myidx = col_idx[base + (lane < mm ? lane : 0)];
        for (int j0 = 0; j0 < mm; j0 += 4) {
            #pragma unroll
            for (int k = 0; k < 4; ++k) {
                int j = j0 + k;
                int jc = j < mm ? j : 0;
                int src = __shfl(myidx, jc);
                float w = (j < mm) ? 1.f : 0.f;
                if constexpr (VEC == 2) {
                    unsigned u = *reinterpret_cast<const unsigned*>(&hs[(size_t)src * F + lane * 2]);
                    acc[0] = fmaf(bfu_lo(u), w, acc[0]);
                    acc[1] = fmaf(bfu_hi(u), w, acc[1]);
                } else {
                    uint2 u = *reinterpret_cast<const uint2*>(&hs[(size_t)src * F + lane * 4]);
                    acc[0] = fmaf(bfu_lo(u.x), w, acc[0]);
                    acc[1] = fmaf(bfu_hi(u.x), w, acc[1]);
                    acc[2] = fmaf(bfu_lo(u.y), w, acc[2]);
                    acc[3] = fmaf(bfu_hi(u.y), w, acc[3]);
                }
            }
        }
    }

    // cross-wave reduce in LDS, wave 0 finalizes
    if (wid > 0) {
        if constexpr (VEC == 2) {
            *reinterpret_cast<float2*>(&red[(wid - 1) * F + lane * 2]) = make_float2(acc[0], acc[1]);
        } else {
            *reinterpret_cast<float4*>(&red[(wid - 1) * F + lane * 4]) =
                make_float4(acc[0], acc[1], acc[2], acc[3]);
        }
    }
    __syncthreads();
    if (wid == 0) {
        #pragma unroll
        for (int w = 0; w < 3; ++w)
            #pragma unroll
            for (int v = 0; v < VEC; ++v) acc[v] += red[w * F + lane * VEC + v];
        float di = dinv[i];
        unsigned short ov[VEC];
        #pragma unroll
        for (int v = 0; v < VEC; ++v) {
            float r = di * acc[v];
            if (BIAS) r += bias[lane * VEC + v];
            if (RELU) r = fmaxf(r, 0.f);
            ov[v] = f2bf(r);
        }
        if constexpr (VEC == 2) {
            *reinterpret_cast<unsigned*>(&out[(size_t)i * F + lane * 2]) =
                (unsigned)ov[0] | ((unsigned)ov[1] << 16);
        } else {
            *reinterpret_cast<ushort4*>(&out[(size_t)i * F + lane * 4]) =
                make_ushort4(ov[0], ov[1], ov[2], ov[3]);
        }
    }
}

// ---------------------------------------------------------------------------
// MFMA bf16 GEMM: C[M,N] = A[M,K] @ W[K,N] (+bias)(relu)(*dinv[row]) -> bf16
// BM=128, BN in {128,64}, BK=64, 256 threads = 4 waves (2x2).
// LDS XOR-swizzled: idx = row*64 + (k ^ ((row&7)<<3)), ushort units.
// ---------------------------------------------------------------------------
template <int K, int N, int BN, bool BIAS, bool RELU, bool SCALE>
__global__ __launch_bounds__(256) void gemm_mfma(const unsigned short* __restrict__ A,
                                                 const unsigned short* __restrict__ WTh,
                                                 const unsigned short* __restrict__ WTl,
                                                 const float* __restrict__ bias,
                                                 const float* __restrict__ dinvp,
                                                 unsigned short* __restrict__ C, int M) {
    constexpr int BM = 128, BK = 64;
    constexpr int WN = BN / 2 / 16;
    __shared__ unsigned short As[BM * BK];
    __shared__ unsigned short Bh[BN * BK];
    __shared__ unsigned short Bl[BN * BK];

    const int tid = threadIdx.x;
    const int wid = tid >> 6;
    const int lane16 = tid & 15;
    const int quad = (tid >> 4) & 3;
    const int wm = (wid >> 1) * 64;
    const int wn = (wid & 1) * (BN / 2);
    const int bm = blockIdx.x * BM;
    const int bn = blockIdx.y * BN;

    f32x4 acc[4][WN];
    #pragma unroll
    for (int mi = 0; mi < 4; ++mi)
        #pragma unroll
        for (int ni = 0; ni < WN; ++ni) acc[mi][ni] = (f32x4)(0.f);

    for (int kt = 0; kt < K / BK; ++kt) {
        #pragma unroll
        for (int c = 0; c < (BM * 8) / 256; ++c) {
            int ch = tid + c * 256;
            int row = ch >> 3, kc = ch & 7;
            int gm = bm + row;
            u16x8 av = (u16x8)(0);
            if (gm < M) av = *reinterpret_cast<const u16x8*>(&A[(size_t)gm * K + kt * BK + kc * 8]);
            *reinterpret_cast<u16x8*>(&As[row * 64 + ((kc * 8) ^ ((row & 7) << 3))]) = av;
        }
        #pragma unroll
        for (int c = 0; c < (2 * BN * 8) / 256; ++c) {
            int ch = tid + c * 256;
            int plane = ch / (BN * 8);
            int r2 = ch % (BN * 8);
            int row = r2 >> 3, kc = r2 & 7;
            const unsigned short* srcp = plane ? WTl : WTh;
            unsigned short* dstp = plane ? Bl : Bh;
            u16x8 bv = *reinterpret_cast<const u16x8*>(&srcp[(size_t)(bn + row) * K + kt * BK + kc * 8]);
            *reinterpret_cast<u16x8*>(&dstp[row * 64 + ((kc * 8) ^ ((row & 7) << 3))]) = bv;
        }
        __syncthreads();

        #pragma unroll
        for (int ks = 0; ks < 2; ++ks) {
            bf16x8 af[4], bfh[WN], bfl[WN];
            #pragma unroll
            for (int mi = 0; mi < 4; ++mi) {
                int row = wm + mi * 16 + lane16;
                int kidx = ks * 32 + quad * 8;
                af[mi] = *reinterpret_cast<bf16x8*>(&As[row * 64 + (kidx ^ ((row & 7) << 3))]);
            }
            #pragma unroll
            for (int ni = 0; ni < WN; ++ni) {
                int row = wn + ni * 16 + lane16;
                int kidx = ks * 32 + quad * 8;
                bfh[ni] = *reinterpret_cast<bf16x8*>(&Bh[row * 64 + (kidx ^ ((row & 7) << 3))]);
                bfl[ni] = *reinterpret_cast<bf16x8*>(&Bl[row * 64 + (kidx ^ ((row & 7) << 3))]);
            }
            #pragma unroll
            for (int mi = 0; mi < 4; ++mi)
                #pragma unroll
                for (int ni = 0; ni < WN; ++ni) {
                    acc[mi][ni] = __builtin_amdgcn_mfma_f32_16x16x32_bf16(af[mi], bfh[ni], acc[mi][ni], 0, 0, 0);
                    acc[mi][ni] = __builtin_amdgcn_mfma_f32_16x16x32_bf16(af[mi], bfl[ni], acc[mi][ni], 0, 0, 0);
                }
        }
        __syncthreads();
    }

    #pragma unroll
    for (int mi = 0; mi < 4; ++mi) {
        #pragma unroll
        for (int r = 0; r < 4; ++r) {
            int gm = bm + wm + mi * 16 + quad * 4 + r;
            if (gm >= M) continue;
            float sc = SCALE ? dinvp[gm] : 1.f;
            #pragma unroll
            for (int ni = 0; ni < WN; ++ni) {
                int gn = bn + wn + ni * 16 + lane16;
                float v = acc[mi][ni][r];
                if (BIAS) v += bias[gn];
                if (RELU) v = fmaxf(v, 0.f);
                if (SCALE) v *= sc;
                C[(size_t)gm * N + gn] = f2bf(v);
            }
        }
    }
}

// pool stage 1: grid (G, 8), 256 threads = 2 rows x 128 cols, rows strided by 16
__global__ void pool_partial_kernel(const unsigned short* __restrict__ A,
                                    const int* __restrict__ gstart,
                                    float* __restrict__ partial) {
    __shared__ float sd[256];
    int g = blockIdx.x, y = blockIdx.y;
    int t = threadIdx.x;
    int c = t & 127, r = t >> 7;
    int s0 = gstart[g], s1 = gstart[g + 1];
    float s = 0.f;
    for (int i = s0 + y * 2 + r; i < s1; i += 16)
        s += bf2f(A[(size_t)i * 128 + c]);
    sd[t] = s;
    __syncthreads();
    if (t < 128) partial[(size_t)(g * 8 + y) * 128 + c] = sd[t] + sd[t + 128];
}

__global__ void pool_reduce_kernel(const float* __restrict__ partial,
                                   const int* __restrict__ gstart,
                                   float* __restrict__ pooled) {
    int g = blockIdx.x, c = threadIdx.x;
    float s = 0.f;
    #pragma unroll
    for (int y = 0; y < 8; ++y) s += partial[(size_t)(g * 8 + y) * 128 + c];
    int cnt = gstart[g + 1] - gstart[g];
    if (cnt < 1) cnt = 1;
    pooled[g * 128 + c] = s / (float)cnt;
}

__global__ void final_kernel(const float* __restrict__ pooled, const float* __restrict__ Wl,
                             const float* __restrict__ bl, float* __restrict__ out) {
    int t = threadIdx.x;
    int g = t >> 1, j = t & 1;
    float s = bl[j];
    #pragma unroll 4
    for (int c = 0; c < 128; ++c) s = fmaf(pooled[g * 128 + c], Wl[c * 2 + j], s);
    out[g * 2 + j] = s;
}

extern "C" void kernel_launch(void* const* d_in, const int* in_sizes, int n_in,
                              void* d_out, int out_size, void* d_ws, size_t ws_size,
                              hipStream_t stream) {
    const float* x   = (const float*)d_in[0];
    const int*   ei  = (const int*)d_in[1];
    const int*   bat = (const int*)d_in[2];
    const float* W1  = (const float*)d_in[3];
    const float* b1  = (const float*)d_in[4];
    const float* W2  = (const float*)d_in[5];
    const float* b2  = (const float*)d_in[6];
    const float* W3  = (const float*)d_in[7];
    const float* b3  = (const float*)d_in[8];
    const float* Wl  = (const float*)d_in[9];
    const float* bl  = (const float*)d_in[10];
    float* out = (float*)d_out;

    const int N = N_NODES_C;
    const int E = in_sizes[1] / 2;
    const int G = N_GRAPHS_C;

    const int* src = ei;
    const int* dst = ei + E;

    // -------- workspace layout --------
    unsigned short* xs  = (unsigned short*)d_ws;         // N*128 bf16 (x*dinv)
    unsigned short* A1b = xs  + (size_t)N * 128;         // N*128
    unsigned short* H1  = A1b + (size_t)N * 128;         // N*512
    unsigned short* T2s = H1  + (size_t)N * 512;         // N*256 ((H1@W2)*dinv)
    unsigned short* H2  = T2s + (size_t)N * 256;         // N*256
    unsigned short* T3s = H2  + (size_t)N * 256;         // N*128 ((H2@W3)*dinv)
    unsigned short* A3  = T3s + (size_t)N * 128;         // N*128
    unsigned short* W1Th = A3 + (size_t)N * 128;         // 512*128
    unsigned short* W1Tl = W1Th + 512 * 128;
    unsigned short* W2Th = W1Tl + 512 * 128;             // 256*512
    unsigned short* W2Tl = W2Th + 256 * 512;
    unsigned short* W3Th = W2Tl + 256 * 512;             // 128*256
    unsigned short* W3Tl = W3Th + 128 * 256;
    int*   deg_cnt = (int*)(W3Tl + 128 * 256);           // N
    int*   row_ptr = deg_cnt + N;                        // N+1
    int*   cursor  = row_ptr + (N + 1);                  // N
    int*   col_idx = cursor + N;                         // E
    float* dinv    = (float*)(col_idx + E);              // N
    int*   gstart  = (int*)(dinv + N);                   // G+1 (+pad)
    float* partial = (float*)(gstart + (G + 4));         // G*8*128
    float* pooled  = partial + (size_t)G * 8 * 128;      // G*128

    // --- build CSR (by dst) + dinv + weight/x conversion ---
    hipMemsetAsync(deg_cnt, 0, N * sizeof(int), stream);
    count_kernel<<<(E + 255) / 256, 256, 0, stream>>>(dst, deg_cnt, E);
    scan_kernel<<<1, 1024, 0, stream>>>(deg_cnt, row_ptr, cursor, dinv, N);
    fill_kernel<<<(E + 255) / 256, 256, 0, stream>>>(src, dst, cursor, col_idx, E);
    bounds_kernel<<<(N + 255) / 256, 256, 0, stream>>>(bat, N, G, gstart);
    wconv_kernel<<<(128 * 512 + 255) / 256, 256, 0, stream>>>(W1, W1Th, W1Tl, 128, 512);
    wconv_kernel<<<(512 * 256 + 255) / 256, 256, 0, stream>>>(W2, W2Th, W2Tl, 512, 256);
    wconv_kernel<<<(256 * 128 + 255) / 256, 256, 0, stream>>>(W3, W3Th, W3Tl, 256, 128);
    xconv_kernel<<<((N * 32) + 255) / 256, 256, 0, stream>>>(x, dinv, xs, N);

    const int MB = (N + 127) / 128;

    // --- layer 1: A1 = Ahat x, H1 = relu(A1 @ W1 + b1) ---
    agg_kernel<128, false, false><<<N, 256, 0, stream>>>(xs, dinv, row_ptr, col_idx, nullptr, A1b, N);
    {
        dim3 grid(MB, 512 / 128);
        gemm_mfma<128, 512, 128, true, true, false><<<grid, 256, 0, stream>>>(A1b, W1Th, W1Tl, b1, nullptr, H1, N);
    }
    // --- layer 2: T2s = (H1 @ W2)*dinv, H2 = relu(dinv*(T2s_i + sum) + b2) ---
    {
        dim3 grid(MB, 256 / 128);
        gemm_mfma<512, 256, 128, false, false, true><<<grid, 256, 0, stream>>>(H1, W2Th, W2Tl, nullptr, dinv, T2s, N);
    }
    agg_kernel<256, true, true><<<N, 256, 0, stream>>>(T2s, dinv, row_ptr, col_idx, b2, H2, N);
    // --- layer 3: T3s = (H2 @ W3)*dinv, A3 = dinv*(T3s_i + sum) + b3 ---
    {
        dim3 grid(MB, 128 / 64);
        gemm_mfma<256, 128, 64, false, false, true><<<grid, 256, 0, stream>>>(H2, W3Th, W3Tl, nullptr, dinv, T3s, N);
    }
    agg_kernel<128, true, false><<<N, 256, 0, stream>>>(T3s, dinv, row_ptr, col_idx, b3, A3, N);

    // --- pool (two-stage) + final linear ---
    {
        dim3 grid(G, 8);
        pool_partial_kernel<<<grid, 256, 0, stream>>>(A3, gstart, partial);
    }
    pool_reduce_kernel<<<G, 128, 0, stream>>>(partial, gstart, pooled);
    final_kernel<<<1, 128, 0, stream>>>(pooled, Wl, bl, out);
}

// Round 5
// 198.674 us; speedup vs baseline: 2.8578x; 1.0944x over previous
//
#include <hip/hip_runtime.h>
#include <hip/hip_bf16.h>

// ---------------------------------------------------------------------------
// GCN: 3x gcn_conv + global_mean_pool + linear
//   h' = D^-1/2 (A+I) D^-1/2 (h W) + b
// Layer1 aggregates BEFORE GEMM ((AX)W == A(XW)), layers 2/3 after.
// dinv FOLDED into stored features; aggregation = pure gather+sum:
//   out[i] = dinv[i]*(hs[i] + sum hs[src]).
// Agg: 1 block/node, 4 waves, HALF-WAVE row gathers (2 edges/wave/step,
// 8-16B per lane), shfl-broadcast indices, unroll-4 (8 gathers in flight).
// GEMMs: bf16 MFMA, W pre-transposed hi/lo split (C = A@Wh + A@Wl);
// BM=64 tiles for the M=20000 GEMMs to fix load balance.
// ---------------------------------------------------------------------------

#define N_NODES_C  20000
#define N_GRAPHS_C 64
#define HID_C      512

typedef __attribute__((ext_vector_type(8))) short bf16x8;
typedef __attribute__((ext_vector_type(8))) unsigned short u16x8;
typedef __attribute__((ext_vector_type(4))) float f32x4;

static __device__ __forceinline__ unsigned short f2bf(float f) {
    __hip_bfloat16 h = __float2bfloat16(f);
    return *reinterpret_cast<unsigned short*>(&h);
}
static __device__ __forceinline__ float bf2f(unsigned short u) {
    __hip_bfloat16 h = *reinterpret_cast<__hip_bfloat16*>(&u);
    return __bfloat162float(h);
}
static __device__ __forceinline__ float bfu_lo(unsigned u) {
    union { unsigned x; float f; } t; t.x = u << 16; return t.f;
}
static __device__ __forceinline__ float bfu_hi(unsigned u) {
    union { unsigned x; float f; } t; t.x = u & 0xffff0000u; return t.f;
}

__global__ void count_kernel(const int* __restrict__ dst, int* __restrict__ deg_cnt, int E) {
    int e = blockIdx.x * blockDim.x + threadIdx.x;
    if (e < E) atomicAdd(&deg_cnt[dst[e]], 1);
}

// Single-block scan via wave shfl: row_ptr/cursor = exclusive prefix, dinv = rsqrt(cnt+1)
__global__ __launch_bounds__(1024) void scan_kernel(const int* __restrict__ deg_cnt,
                                                    int* __restrict__ row_ptr,
                                                    int* __restrict__ cursor,
                                                    float* __restrict__ dinv, int n) {
    __shared__ int ws[16];
    int t = threadIdx.x;
    int wid = t >> 6, lane = t & 63;
    int carry = 0;
    for (int base = 0; base < n; base += 1024) {
        int idx = base + t;
        int v = (idx < n) ? deg_cnt[idx] : 0;
        int x = v;
        #pragma unroll
        for (int off = 1; off < 64; off <<= 1) {
            int y = __shfl_up(x, off);
            if (lane >= off) x += y;
        }
        if (lane == 63) ws[wid] = x;
        __syncthreads();
        if (wid == 0 && lane < 16) {
            int w = ws[lane];
            #pragma unroll
            for (int off = 1; off < 16; off <<= 1) {
                int y = __shfl_up(w, off);
                if (lane >= off) w += y;
            }
            ws[lane] = w;
        }
        __syncthreads();
        int wave_excl = (wid == 0) ? 0 : ws[wid - 1];
        int total = ws[15];
        if (idx < n) {
            int rp = carry + wave_excl + (x - v);
            row_ptr[idx] = rp;
            cursor[idx]  = rp;
            dinv[idx]    = rsqrtf((float)(v + 1));
        }
        carry += total;
        __syncthreads();
    }
    if (t == 0) row_ptr[n] = carry;
}

static __device__ __forceinline__ void wsplit_body(const float* __restrict__ W, int i,
                                                   int Kd, int Nd,
                                                   unsigned short* __restrict__ WTh,
                                                   unsigned short* __restrict__ WTl) {
    int k = i / Nd, n = i % Nd;
    float v = W[i];
    unsigned short hi = f2bf(v);
    unsigned short lo = f2bf(v - bf2f(hi));
    WTh[(size_t)n * Kd + k] = hi;
    WTl[(size_t)n * Kd + k] = lo;
}

// Fused: 3x weight transpose+split + graph-boundary detection (independent of CSR)
__global__ void prep_kernel(const float* __restrict__ W1, const float* __restrict__ W2,
                            const float* __restrict__ W3,
                            unsigned short* __restrict__ W1Th, unsigned short* __restrict__ W1Tl,
                            unsigned short* __restrict__ W2Th, unsigned short* __restrict__ W2Tl,
                            unsigned short* __restrict__ W3Th, unsigned short* __restrict__ W3Tl,
                            const int* __restrict__ batch, int n, int ngraphs,
                            int* __restrict__ gstart) {
    int t = blockIdx.x * blockDim.x + threadIdx.x;
    if (t < 128 * 512) {
        wsplit_body(W1, t, 128, 512, W1Th, W1Tl);
    } else if (t < 128 * 512 + 512 * 256) {
        wsplit_body(W2, t - 128 * 512, 512, 256, W2Th, W2Tl);
    } else if (t < 128 * 512 + 512 * 256 + 256 * 128) {
        wsplit_body(W3, t - (128 * 512 + 512 * 256), 256, 128, W3Th, W3Tl);
    } else {
        int i = t - (128 * 512 + 512 * 256 + 256 * 128);
        if (i >= n) return;
        int b = batch[i];
        if (i == 0) {
            for (int g = 0; g <= b; ++g) gstart[g] = 0;
        } else {
            int bp = batch[i - 1];
            if (bp != b) for (int g = bp + 1; g <= b; ++g) gstart[g] = i;
        }
        if (i == n - 1) {
            for (int g = b + 1; g <= ngraphs; ++g) gstart[g] = n;
        }
    }
}

// Fused: CSR fill (scatter) + xs = bf16(x*dinv)
__global__ void fillx_kernel(const int* __restrict__ src, const int* __restrict__ dst,
                             int* __restrict__ cursor, int* __restrict__ col_idx, int E,
                             const float* __restrict__ x, const float* __restrict__ dinv,
                             unsigned short* __restrict__ xs, int nrows) {
    int t = blockIdx.x * blockDim.x + threadIdx.x;
    if (t < E) {
        int d = dst[t];
        int pos = atomicAdd(&cursor[d], 1);
        col_idx[pos] = src[t];
    } else {
        int u = t - E;
        int row = u >> 5, q = u & 31;
        if (row >= nrows) return;
        float di = dinv[row];
        f32x4 v = *reinterpret_cast<const f32x4*>(&x[(size_t)row * 128 + q * 4]);
        ushort4 o;
        o.x = f2bf(v.x * di); o.y = f2bf(v.y * di);
        o.z = f2bf(v.z * di); o.w = f2bf(v.w * di);
        *reinterpret_cast<ushort4*>(&xs[(size_t)row * 128 + q * 4]) = o;
    }
}

// ---------------------------------------------------------------------------
// Aggregation: out[i] = dinv[i]*(hs[i] + sum_{e in(i)} hs[src]) (+bias)(relu)
// Half-wave scheme: lanes 0-31 handle edge 2p, lanes 32-63 edge 2p+1; each
// lane loads CPL=F/32 bf16 (8B/16B). Unroll 4 pairs -> 8 gathers in flight.
// ---------------------------------------------------------------------------
template <int F, bool BIAS, bool RELU>
__global__ __launch_bounds__(256) void agg_kernel(const unsigned short* __restrict__ hs,
                                                  const float* __restrict__ dinv,
                                                  const int* __restrict__ row_ptr,
                                                  const int* __restrict__ col_idx,
                                                  const float* __restrict__ bias,
                                                  unsigned short* __restrict__ out, int n) {
    constexpr int CPL = F / 32;         // bf16 per lane: 4 (F=128) or 8 (F=256)
    __shared__ float red[3 * F];
    int i = blockIdx.x;
    int tid = threadIdx.x;
    int wid = tid >> 6, lane = tid & 63;
    int h = lane >> 5, l32 = lane & 31;
    int e0 = row_ptr[i], e1 = row_ptr[i + 1];
    int deg = e1 - e0;

    float acc[CPL];
    #pragma unroll
    for (int v = 0; v < CPL; ++v) acc[v] = 0.f;

    // wave 0, half 0 seeds with the self row
    if (wid == 0 && h == 0) {
        const unsigned short* p = &hs[(size_t)i * F + l32 * CPL];
        if constexpr (CPL == 4) {
            uint2 u = *reinterpret_cast<const uint2*>(p);
            acc[0] = bfu_lo(u.x); acc[1] = bfu_hi(u.x);
            acc[2] = bfu_lo(u.y); acc[3] = bfu_hi(u.y);
        } else {
            uint4 u = *reinterpret_cast<const uint4*>(p);
            acc[0] = bfu_lo(u.x); acc[1] = bfu_hi(u.x);
            acc[2] = bfu_lo(u.y); acc[3] = bfu_hi(u.y);
            acc[4] = bfu_lo(u.z); acc[5] = bfu_hi(u.z);
            acc[6] = bfu_lo(u.w); acc[7] = bfu_hi(u.w);
        }
    }

    // contiguous edge chunk per wave; 2 edges per step (one per half-wave)
    int per = (deg + 3) >> 2;
    int cs = e0 + wid * per;
    int ce = cs + per; if (ce > e1) ce = e1;
    for (int base = cs; base < ce; base += 64) {
        int rem = ce - base;
        int mm = rem < 64 ? rem : 64;
        int myidx = col_idx[base + (lane < mm ? lane : 0)];
        for (int p0 = 0; 2 * p0 < mm; p0 += 4) {
            #pragma unroll
            for (int k = 0; k < 4; ++k) {
                int j = 2 * (p0 + k) + h;
                int jc = j < mm ? j : 0;
                int srcn = __shfl(myidx, jc);
                float w = (j < mm) ? 1.f : 0.f;
                const unsigned short* p = &hs[(size_t)srcn * F + l32 * CPL];
                if constexpr (CPL == 4) {
                    uint2 u = *reinterpret_cast<const uint2*>(p);
                    acc[0] = fmaf(bfu_lo(u.x), w, acc[0]);
                    acc[1] = fmaf(bfu_hi(u.x), w, acc[1]);
                    acc[2] = fmaf(bfu_lo(u.y), w, acc[2]);
                    acc[3] = fmaf(bfu_hi(u.y), w, acc[3]);
                } else {
                    uint4 u = *reinterpret_cast<const uint4*>(p);
                    acc[0] = fmaf(bfu_lo(u.x), w, acc[0]);
                    acc[1] = fmaf(bfu_hi(u.x), w, acc[1]);
                    acc[2] = fmaf(bfu_lo(u.y), w, acc[2]);
                    acc[3] = fmaf(bfu_hi(u.y), w, acc[3]);
                    acc[4] = fmaf(bfu_lo(u.z), w, acc[4]);
                    acc[5] = fmaf(bfu_hi(u.z), w, acc[5]);
                    acc[6] = fmaf(bfu_lo(u.w), w, acc[6]);
                    acc[7] = fmaf(bfu_hi(u.w), w, acc[7]);
                }
            }
        }
    }

    // fold the two half-waves
    #pragma unroll
    for (int v = 0; v < CPL; ++v) acc[v] += __shfl_xor(acc[v], 32);

    // cross-wave reduce in LDS (half 0 lanes only), wave 0 finalizes
    if (wid > 0 && h == 0) {
        float* r = &red[(wid - 1) * F + l32 * CPL];
        #pragma unroll
        for (int v = 0; v < CPL; v += 4)
            *reinterpret_cast<float4*>(&r[v]) = make_float4(acc[v], acc[v+1], acc[v+2], acc[v+3]);
    }
    __syncthreads();
    if (wid == 0 && h == 0) {
        #pragma unroll
        for (int w = 0; w < 3; ++w)
            #pragma unroll
            for (int v = 0; v < CPL; ++v) acc[v] += red[w * F + l32 * CPL + v];
        float di = dinv[i];
        unsigned short ov[CPL];
        #pragma unroll
        for (int v = 0; v < CPL; ++v) {
            float r = di * acc[v];
            if (BIAS) r += bias[l32 * CPL + v];
            if (RELU) r = fmaxf(r, 0.f);
            ov[v] = f2bf(r);
        }
        if constexpr (CPL == 4) {
            uint2 o;
            o.x = (unsigned)ov[0] | ((unsigned)ov[1] << 16);
            o.y = (unsigned)ov[2] | ((unsigned)ov[3] << 16);
            *reinterpret_cast<uint2*>(&out[(size_t)i * F + l32 * CPL]) = o;
        } else {
            uint4 o;
            o.x = (unsigned)ov[0] | ((unsigned)ov[1] << 16);
            o.y = (unsigned)ov[2] | ((unsigned)ov[3] << 16);
            o.z = (unsigned)ov[4] | ((unsigned)ov[5] << 16);
            o.w = (unsigned)ov[6] | ((unsigned)ov[7] << 16);
            *reinterpret_cast<uint4*>(&out[(size_t)i * F + l32 * CPL]) = o;
        }
    }
}

// ---------------------------------------------------------------------------
// MFMA bf16 GEMM: C[M,N] = A[M,K] @ W[K,N] (+bias)(relu)(*dinv[row]) -> bf16
// BM in {128,64}, BN in {128,64}, BK=64, 256 threads = 4 waves (2x2).
// LDS XOR-swizzled: idx = row*64 + (k ^ ((row&7)<<3)), ushort units.
// ---------------------------------------------------------------------------
template <int K, int N, int BM, int BN, bool BIAS, bool RELU, bool SCALE>
__global__ __launch_bounds__(256) void gemm_mfma(const unsigned short* __restrict__ A,
                                                 const unsigned short* __restrict__ WTh,
                                                 const unsigned short* __restrict__ WTl,
                                                 const float* __restrict__ bias,
                                                 const float* __restrict__ dinvp,
                                                 unsigned short* __restrict__ C, int M) {
    constexpr int BK = 64;
    constexpr int MI = BM / 32;               // m-frags per wave (4 or 2)
    constexpr int WN = BN / 2 / 16;           // n-frags per wave (4 or 2)
    __shared__ unsigned short As[BM * BK];
    __shared__ unsigned short Bh[BN * BK];
    __shared__ unsigned short Bl[BN * BK];

    const int tid = threadIdx.x;
    const int wid = tid >> 6;
    const int lane16 = tid & 15;
    const int quad = (tid >> 4) & 3;
    const int wm = (wid >> 1) * (BM / 2);
    const int wn = (wid & 1) * (BN / 2);
    const int bm = blockIdx.x * BM;
    const int bn = blockIdx.y * BN;

    f32x4 acc[MI][WN];
    #pragma unroll
    for (int mi = 0; mi < MI; ++mi)
        #pragma unroll
        for (int ni = 0; ni < WN; ++ni) acc[mi][ni] = (f32x4)(0.f);

    for (int kt = 0; kt < K / BK; ++kt) {
        #pragma unroll
        for (int c = 0; c < (BM * 8) / 256; ++c) {
            int ch = tid + c * 256;
            int row = ch >> 3, kc = ch & 7;
            int gm = bm + row;
            u16x8 av = (u16x8)(0);
            if (gm < M) av = *reinterpret_cast<const u16x8*>(&A[(size_t)gm * K + kt * BK + kc * 8]);
            *reinterpret_cast<u16x8*>(&As[row * 64 + ((kc * 8) ^ ((row & 7) << 3))]) = av;
        }
        #pragma unroll
        for (int c = 0; c < (2 * BN * 8) / 256; ++c) {
            int ch = tid + c * 256;
            int plane = ch / (BN * 8);
            int r2 = ch % (BN * 8);
            int row = r2 >> 3, kc = r2 & 7;
            const unsigned short* srcp = plane ? WTl : WTh;
            unsigned short* dstp = plane ? Bl : Bh;
            u16x8 bv = *reinterpret_cast<const u16x8*>(&srcp[(size_t)(bn + row) * K + kt * BK + kc * 8]);
            *reinterpret_cast<u16x8*>(&dstp[row * 64 + ((kc * 8) ^ ((row & 7) << 3))]) = bv;
        }
        __syncthreads();

        #pragma unroll
        for (int ks = 0; ks < 2; ++ks) {
            bf16x8 af[MI], bfh[WN], bfl[WN];
            #pragma unroll
            for (int mi = 0; mi < MI; ++mi) {
                int row = wm + mi * 16 + lane16;
                int kidx = ks * 32 + quad * 8;
                af[mi] = *reinterpret_cast<bf16x8*>(&As[row * 64 + (kidx ^ ((row & 7) << 3))]);
            }
            #pragma unroll
            for (int ni = 0; ni < WN; ++ni) {
                int row = wn + ni * 16 + lane16;
                int kidx = ks * 32 + quad * 8;
                bfh[ni] = *reinterpret_cast<bf16x8*>(&Bh[row * 64 + (kidx ^ ((row & 7) << 3))]);
                bfl[ni] = *reinterpret_cast<bf16x8*>(&Bl[row * 64 + (kidx ^ ((row & 7) << 3))]);
            }
            #pragma unroll
            for (int mi = 0; mi < MI; ++mi)
                #pragma unroll
                for (int ni = 0; ni < WN; ++ni) {
                    acc[mi][ni] = __builtin_amdgcn_mfma_f32_16x16x32_bf16(af[mi], bfh[ni], acc[mi][ni], 0, 0, 0);
                    acc[mi][ni] = __builtin_amdgcn_mfma_f32_16x16x32_bf16(af[mi], bfl[ni], acc[mi][ni], 0, 0, 0);
                }
        }
        __syncthreads();
    }

    #pragma unroll
    for (int mi = 0; mi < MI; ++mi) {
        #pragma unroll
        for (int r = 0; r < 4; ++r) {
            int gm = bm + wm + mi * 16 + quad * 4 + r;
            if (gm >= M) continue;
            float sc = SCALE ? dinvp[gm] : 1.f;
            #pragma unroll
            for (int ni = 0; ni < WN; ++ni) {
                int gn = bn + wn + ni * 16 + lane16;
                float v = acc[mi][ni][r];
                if (BIAS) v += bias[gn];
                if (RELU) v = fmaxf(v, 0.f);
                if (SCALE) v *= sc;
                C[(size_t)gm * N + gn] = f2bf(v);
            }
        }
    }
}

// pool stage 1: grid (G, 8), 256 threads = 2 rows x 128 cols, rows strided by 16
__global__ void pool_partial_kernel(const unsigned short* __restrict__ A,
                                    const int* __restrict__ gstart,
                                    float* __restrict__ partial) {
    __shared__ float sd[256];
    int g = blockIdx.x, y = blockIdx.y;
    int t = threadIdx.x;
    int c = t & 127, r = t >> 7;
    int s0 = gstart[g], s1 = gstart[g + 1];
    float s = 0.f;
    for (int i = s0 + y * 2 + r; i < s1; i += 16)
        s += bf2f(A[(size_t)i * 128 + c]);
    sd[t] = s;
    __syncthreads();
    if (t < 128) partial[(size_t)(g * 8 + y) * 128 + c] = sd[t] + sd[t + 128];
}

__global__ void pool_reduce_kernel(const float* __restrict__ partial,
                                   const int* __restrict__ gstart,
                                   float* __restrict__ pooled) {
    int g = blockIdx.x, c = threadIdx.x;
    float s = 0.f;
    #pragma unroll
    for (int y = 0; y < 8; ++y) s += partial[(size_t)(g * 8 + y) * 128 + c];
    int cnt = gstart[g + 1] - gstart[g];
    if (cnt < 1) cnt = 1;
    pooled[g * 128 + c] = s / (float)cnt;
}

__global__ void final_kernel(const float* __restrict__ pooled, const float* __restrict__ Wl,
                             const float* __restrict__ bl, float* __restrict__ out) {
    int t = threadIdx.x;
    int g = t >> 1, j = t & 1;
    float s = bl[j];
    #pragma unroll 4
    for (int c = 0; c < 128; ++c) s = fmaf(pooled[g * 128 + c], Wl[c * 2 + j], s);
    out[g * 2 + j] = s;
}

extern "C" void kernel_launch(void* const* d_in, const int* in_sizes, int n_in,
                              void* d_out, int out_size, void* d_ws, size_t ws_size,
                              hipStream_t stream) {
    const float* x   = (const float*)d_in[0];
    const int*   ei  = (const int*)d_in[1];
    const int*   bat = (const int*)d_in[2];
    const float* W1  = (const float*)d_in[3];
    const float* b1  = (const float*)d_in[4];
    const float* W2  = (const float*)d_in[5];
    const float* b2  = (const float*)d_in[6];
    const float* W3  = (const float*)d_in[7];
    const float* b3  = (const float*)d_in[8];
    const float* Wl  = (const float*)d_in[9];
    const float* bl  = (const float*)d_in[10];
    float* out = (float*)d_out;

    const int N = N_NODES_C;
    const int E = in_sizes[1] / 2;
    const int G = N_GRAPHS_C;

    const int* src = ei;
    const int* dst = ei + E;

    // -------- workspace layout --------
    unsigned short* xs  = (unsigned short*)d_ws;         // N*128 bf16 (x*dinv)
    unsigned short* A1b = xs  + (size_t)N * 128;         // N*128
    unsigned short* H1  = A1b + (size_t)N * 128;         // N*512
    unsigned short* T2s = H1  + (size_t)N * 512;         // N*256 ((H1@W2)*dinv)
    unsigned short* H2  = T2s + (size_t)N * 256;         // N*256
    unsigned short* T3s = H2  + (size_t)N * 256;         // N*128 ((H2@W3)*dinv)
    unsigned short* A3  = T3s + (size_t)N * 128;         // N*128
    unsigned short* W1Th = A3 + (size_t)N * 128;         // 512*128
    unsigned short* W1Tl = W1Th + 512 * 128;
    unsigned short* W2Th = W1Tl + 512 * 128;             // 256*512
    unsigned short* W2Tl = W2Th + 256 * 512;
    unsigned short* W3Th = W2Tl + 256 * 512;             // 128*256
    unsigned short* W3Tl = W3Th + 128 * 256;
    int*   deg_cnt = (int*)(W3Tl + 128 * 256);           // N
    int*   row_ptr = deg_cnt + N;                        // N+1
    int*   cursor  = row_ptr + (N + 1);                  // N
    int*   col_idx = cursor + N;                         // E
    float* dinv    = (float*)(col_idx + E);              // N
    int*   gstart  = (int*)(dinv + N);                   // G+1 (+pad)
    float* partial = (float*)(gstart + (G + 4));         // G*8*128
    float* pooled  = partial + (size_t)G * 8 * 128;      // G*128

    // --- setup: CSR (by dst) + dinv + fused weight/bounds/x conversion ---
    hipMemsetAsync(deg_cnt, 0, N * sizeof(int), stream);
    count_kernel<<<(E + 255) / 256, 256, 0, stream>>>(dst, deg_cnt, E);
    {
        int total = 128 * 512 + 512 * 256 + 256 * 128 + N;
        prep_kernel<<<(total + 255) / 256, 256, 0, stream>>>(W1, W2, W3, W1Th, W1Tl,
                                                             W2Th, W2Tl, W3Th, W3Tl,
                                                             bat, N, G, gstart);
    }
    scan_kernel<<<1, 1024, 0, stream>>>(deg_cnt, row_ptr, cursor, dinv, N);
    {
        int total = E + N * 32;
        fillx_kernel<<<(total + 255) / 256, 256, 0, stream>>>(src, dst, cursor, col_idx, E,
                                                              x, dinv, xs, N);
    }

    const int MB128 = (N + 127) / 128;   // 157
    const int MB64  = (N + 63) / 64;     // 313

    // --- layer 1: A1 = Ahat x, H1 = relu(A1 @ W1 + b1) ---
    agg_kernel<128, false, false><<<N, 256, 0, stream>>>(xs, dinv, row_ptr, col_idx, nullptr, A1b, N);
    {
        dim3 grid(MB128, 512 / 128);
        gemm_mfma<128, 512, 128, 128, true, true, false><<<grid, 256, 0, stream>>>(A1b, W1Th, W1Tl, b1, nullptr, H1, N);
    }
    // --- layer 2: T2s = (H1 @ W2)*dinv, H2 = relu(dinv*(T2s_i + sum) + b2) ---
    {
        dim3 grid(MB64, 256 / 128);
        gemm_mfma<512, 256, 64, 128, false, false, true><<<grid, 256, 0, stream>>>(H1, W2Th, W2Tl, nullptr, dinv, T2s, N);
    }
    agg_kernel<256, true, true><<<N, 256, 0, stream>>>(T2s, dinv, row_ptr, col_idx, b2, H2, N);
    // --- layer 3: T3s = (H2 @ W3)*dinv, A3 = dinv*(T3s_i + sum) + b3 ---
    {
        dim3 grid(MB64, 128 / 64);
        gemm_mfma<256, 128, 64, 64, false, false, true><<<grid, 256, 0, stream>>>(H2, W3Th, W3Tl, nullptr, dinv, T3s, N);
    }
    agg_kernel<128, true, false><<<N, 256, 0, stream>>>(T3s, dinv, row_ptr, col_idx, b3, A3, N);

    // --- pool (two-stage) + final linear ---
    {
        dim3 grid(G, 8);
        pool_partial_kernel<<<grid, 256, 0, stream>>>(A3, gstart, partial);
    }
    pool_reduce_kernel<<<G, 128, 0, stream>>>(partial, gstart, pooled);
    final_kernel<<<1, 128, 0, stream>>>(pooled, Wl, bl, out);
}